// Round 1
// baseline (53001.062 us; speedup 1.0000x reference)
//
#include <hip/hip_runtime.h>
#include <math.h>

// Model dims
#define Bn  4
#define Tn  1024
#define Dn  1024
#define Hn  16
#define Lnum 12
#define HDn 64
#define FFn 4096
#define Vn  32000
#define NTOK (Bn*Tn)   // 4096

// ---------------------------------------------------------------- embed
__global__ __launch_bounds__(256) void embed_kernel(
    const int* __restrict__ idx, const float* __restrict__ tok,
    const float* __restrict__ pos, float* __restrict__ x)
{
    int i = blockIdx.x * 256 + threadIdx.x;     // over NTOK*Dn/4 float4s
    int d4 = i & 255;                           // Dn/4 = 256
    int bt = i >> 8;
    int t  = bt & (Tn - 1);
    int row = idx[bt];
    float4 tv = ((const float4*)(tok + (size_t)row * Dn))[d4];
    float4 pv = ((const float4*)(pos + (size_t)t * Dn))[d4];
    float4 o;
    o.x = tv.x + pv.x; o.y = tv.y + pv.y; o.z = tv.z + pv.z; o.w = tv.w + pv.w;
    ((float4*)x)[i] = o;
}

// ---------------------------------------------------------------- layernorm
__global__ __launch_bounds__(256) void ln_kernel(
    const float* __restrict__ x, const float* __restrict__ g,
    const float* __restrict__ b, float* __restrict__ y)
{
    int row = blockIdx.x;
    int tid = threadIdx.x;
    const float4* xr = (const float4*)(x + (size_t)row * Dn);
    float4 v = xr[tid];
    float s  = v.x + v.y + v.z + v.w;
    float ss = v.x*v.x + v.y*v.y + v.z*v.z + v.w*v.w;
    #pragma unroll
    for (int m = 1; m < 64; m <<= 1) {
        s  += __shfl_xor(s,  m);
        ss += __shfl_xor(ss, m);
    }
    __shared__ float sh_s[4], sh_ss[4];
    int wave = tid >> 6, lane = tid & 63;
    if (lane == 0) { sh_s[wave] = s; sh_ss[wave] = ss; }
    __syncthreads();
    s  = sh_s[0] + sh_s[1] + sh_s[2] + sh_s[3];
    ss = sh_ss[0] + sh_ss[1] + sh_ss[2] + sh_ss[3];
    float mean = s * (1.0f / Dn);
    float var  = ss * (1.0f / Dn) - mean * mean;
    float rstd = rsqrtf(var + 1e-5f);
    float4 gv = ((const float4*)g)[tid];
    float4 bv = ((const float4*)b)[tid];
    float4 o;
    o.x = (v.x - mean) * rstd * gv.x + bv.x;
    o.y = (v.y - mean) * rstd * gv.y + bv.y;
    o.z = (v.z - mean) * rstd * gv.z + bv.z;
    o.w = (v.w - mean) * rstd * gv.w + bv.w;
    ((float4*)(y + (size_t)row * Dn))[tid] = o;
}

// ---------------------------------------------------------------- generic GEMM
// C[M,N] = act(A[M,K] @ W[K,N] + bias) (+ res). 64x64 tile, BK=16, 256 thr.
__device__ __forceinline__ float gelu_exact(float v) {
    return 0.5f * v * (1.0f + erff(v * 0.70710678118654752f));
}

template<int ACT, bool HAS_RES>
__global__ __launch_bounds__(256) void gemm_kernel(
    const float* __restrict__ A, const float* __restrict__ W,
    const float* __restrict__ bias, const float* __restrict__ res,
    float* __restrict__ C, int M, int N, int K)
{
    __shared__ float As[16][68];   // [k][m], padded: 2-way-max store conflicts, 16B-aligned rows
    __shared__ float Ws[16][64];   // [k][n]
    int tid = threadIdx.x;
    int bm = blockIdx.y, bn = blockIdx.x;
    int arow = tid >> 2;              // 0..63
    int ak4  = (tid & 3) * 4;         // 0,4,8,12
    int wrow = tid >> 4;              // 0..15 (k)
    int wn4  = (tid & 15) * 4;        // 0..60
    const float* Aptr = A + ((size_t)(bm * 64 + arow)) * K + ak4;
    const float* Wptr = W + (size_t)wrow * N + (size_t)bn * 64 + wn4;
    int ty = tid >> 4, tx = tid & 15;
    float c[4][4] = {};
    for (int k0 = 0; k0 < K; k0 += 16) {
        float4 av = *(const float4*)Aptr; Aptr += 16;
        float4 wv = *(const float4*)Wptr; Wptr += (size_t)16 * N;
        As[ak4 + 0][arow] = av.x;
        As[ak4 + 1][arow] = av.y;
        As[ak4 + 2][arow] = av.z;
        As[ak4 + 3][arow] = av.w;
        *(float4*)&Ws[wrow][wn4] = wv;
        __syncthreads();
        #pragma unroll
        for (int kk = 0; kk < 16; ++kk) {
            float4 a = *(const float4*)&As[kk][ty * 4];
            float4 w = *(const float4*)&Ws[kk][tx * 4];
            c[0][0] += a.x * w.x; c[0][1] += a.x * w.y; c[0][2] += a.x * w.z; c[0][3] += a.x * w.w;
            c[1][0] += a.y * w.x; c[1][1] += a.y * w.y; c[1][2] += a.y * w.z; c[1][3] += a.y * w.w;
            c[2][0] += a.z * w.x; c[2][1] += a.z * w.y; c[2][2] += a.z * w.z; c[2][3] += a.z * w.w;
            c[3][0] += a.w * w.x; c[3][1] += a.w * w.y; c[3][2] += a.w * w.z; c[3][3] += a.w * w.w;
        }
        __syncthreads();
    }
    int ccol = bn * 64 + tx * 4;
    float4 bv = *(const float4*)(bias + ccol);
    #pragma unroll
    for (int i = 0; i < 4; ++i) {
        size_t off = (size_t)(bm * 64 + ty * 4 + i) * N + ccol;
        float4 o;
        o.x = c[i][0] + bv.x; o.y = c[i][1] + bv.y;
        o.z = c[i][2] + bv.z; o.w = c[i][3] + bv.w;
        if (ACT == 1) {
            o.x = gelu_exact(o.x); o.y = gelu_exact(o.y);
            o.z = gelu_exact(o.z); o.w = gelu_exact(o.w);
        }
        if (HAS_RES) {
            float4 r = *(const float4*)(res + off);
            o.x += r.x; o.y += r.y; o.z += r.z; o.w += r.w;
        }
        *(float4*)(C + off) = o;
    }
}

// ---------------------------------------------------------------- QKV GEMM
// h[4096,1024] @ wqkv_l[(s,h),1024,64] -> q/k/v as [B,H,T,64]
// blockIdx.x in 0..47: s = x>>4 (0=key,1=query,2=value), head = x&15
__global__ __launch_bounds__(256) void gemm_qkv_kernel(
    const float* __restrict__ A, const float* __restrict__ Wl,
    float* __restrict__ qb, float* __restrict__ kb, float* __restrict__ vb)
{
    __shared__ float As[16][68];
    __shared__ float Ws[16][64];
    int tid = threadIdx.x;
    int bm = blockIdx.y, bn = blockIdx.x;
    int s = bn >> 4, head = bn & 15;
    const float* W = Wl + ((size_t)(s * Hn + head)) * Dn * HDn;  // [1024][64]
    float* outp = (s == 0) ? kb : ((s == 1) ? qb : vb);
    int arow = tid >> 2;
    int ak4  = (tid & 3) * 4;
    int wrow = tid >> 4;
    int wn4  = (tid & 15) * 4;
    const float* Aptr = A + ((size_t)(bm * 64 + arow)) * Dn + ak4;
    const float* Wptr = W + (size_t)wrow * 64 + wn4;
    int ty = tid >> 4, tx = tid & 15;
    float c[4][4] = {};
    for (int k0 = 0; k0 < Dn; k0 += 16) {
        float4 av = *(const float4*)Aptr; Aptr += 16;
        float4 wv = *(const float4*)Wptr; Wptr += 16 * 64;
        As[ak4 + 0][arow] = av.x;
        As[ak4 + 1][arow] = av.y;
        As[ak4 + 2][arow] = av.z;
        As[ak4 + 3][arow] = av.w;
        *(float4*)&Ws[wrow][wn4] = wv;
        __syncthreads();
        #pragma unroll
        for (int kk = 0; kk < 16; ++kk) {
            float4 a = *(const float4*)&As[kk][ty * 4];
            float4 w = *(const float4*)&Ws[kk][tx * 4];
            c[0][0] += a.x * w.x; c[0][1] += a.x * w.y; c[0][2] += a.x * w.z; c[0][3] += a.x * w.w;
            c[1][0] += a.y * w.x; c[1][1] += a.y * w.y; c[1][2] += a.y * w.z; c[1][3] += a.y * w.w;
            c[2][0] += a.z * w.x; c[2][1] += a.z * w.y; c[2][2] += a.z * w.z; c[2][3] += a.z * w.w;
            c[3][0] += a.w * w.x; c[3][1] += a.w * w.y; c[3][2] += a.w * w.z; c[3][3] += a.w * w.w;
        }
        __syncthreads();
    }
    #pragma unroll
    for (int i = 0; i < 4; ++i) {
        int row = bm * 64 + ty * 4 + i;       // = b*Tn + t
        int b = row >> 10, t = row & (Tn - 1);
        size_t off = ((size_t)(b * Hn + head) * Tn + t) * HDn + tx * 4;
        float4 o;
        o.x = c[i][0]; o.y = c[i][1]; o.z = c[i][2]; o.w = c[i][3];
        *(float4*)(outp + off) = o;
    }
}

// ---------------------------------------------------------------- attention
// one wave per query row; online softmax; q/k/v in [B,H,T,64]
// output written directly in concat layout [B,T,D] (d = h*64 + lane)
__global__ __launch_bounds__(256) void attn_kernel(
    const float* __restrict__ q, const float* __restrict__ k,
    const float* __restrict__ v, float* __restrict__ o)
{
    int wave = threadIdx.x >> 6;
    int lane = threadIdx.x & 63;
    int qrow = blockIdx.x * 4 + wave;     // 0..B*H*T-1
    int bh = qrow >> 10;                  // b*H + h
    int t  = qrow & (Tn - 1);
    int b  = bh >> 4, h = bh & 15;
    const float* kp = k + (size_t)bh * Tn * HDn;
    const float* vp = v + (size_t)bh * Tn * HDn;
    float qv = q[((size_t)bh * Tn + t) * HDn + lane] * 0.03125f;  // scale = D^-0.5 = 1/32
    float m = -INFINITY, l = 0.0f, acc = 0.0f;
    for (int j = 0; j <= t; ++j) {
        float kf = kp[(size_t)j * HDn + lane];
        float vf = vp[(size_t)j * HDn + lane];
        float sc = qv * kf;
        #pragma unroll
        for (int msk = 1; msk < 64; msk <<= 1) sc += __shfl_xor(sc, msk);
        float mn = fmaxf(m, sc);
        float p = __expf(sc - mn);
        float alpha = __expf(m - mn);
        l = l * alpha + p;
        acc = acc * alpha + p * vf;
        m = mn;
    }
    o[((size_t)(b * Tn + t)) * Dn + h * HDn + lane] = acc / l;
}

// ---------------------------------------------------------------- launch
extern "C" void kernel_launch(void* const* d_in, const int* in_sizes, int n_in,
                              void* d_out, int out_size, void* d_ws, size_t ws_size,
                              hipStream_t stream)
{
    const int*   idx  = (const int*)  d_in[0];
    const float* tok  = (const float*)d_in[1];
    const float* pos  = (const float*)d_in[2];
    const float* wqkv = (const float*)d_in[3];
    const float* wo   = (const float*)d_in[4];
    const float* bo   = (const float*)d_in[5];
    const float* ln1g = (const float*)d_in[6];
    const float* ln1b = (const float*)d_in[7];
    const float* ln2g = (const float*)d_in[8];
    const float* ln2b = (const float*)d_in[9];
    const float* w1   = (const float*)d_in[10];
    const float* b1   = (const float*)d_in[11];
    const float* w2   = (const float*)d_in[12];
    const float* b2   = (const float*)d_in[13];
    const float* lnfg = (const float*)d_in[14];
    const float* lnfb = (const float*)d_in[15];
    const float* lmw  = (const float*)d_in[16];
    const float* lmb  = (const float*)d_in[17];
    float* out = (float*)d_out;
    float* ws  = (float*)d_ws;

    const size_t XD = (size_t)NTOK * Dn;   // 4.19M floats
    float* x   = ws;
    float* h   = ws + XD;
    float* qb  = ws + 2 * XD;
    float* kb  = ws + 3 * XD;
    float* vb  = ws + 4 * XD;
    float* ao  = ws + 5 * XD;
    float* mid = ws + 2 * XD;              // aliases q/k/v/ao (disjoint lifetime), 4*XD floats

    embed_kernel<<<dim3(NTOK * Dn / 4 / 256), dim3(256), 0, stream>>>(idx, tok, pos, x);

    for (int l = 0; l < Lnum; ++l) {
        ln_kernel<<<dim3(NTOK), dim3(256), 0, stream>>>(x, ln1g + l * Dn, ln1b + l * Dn, h);
        gemm_qkv_kernel<<<dim3(48, NTOK / 64), dim3(256), 0, stream>>>(
            h, wqkv + (size_t)l * 3 * Hn * Dn * HDn, qb, kb, vb);
        attn_kernel<<<dim3(Bn * Hn * Tn / 4), dim3(256), 0, stream>>>(qb, kb, vb, ao);
        gemm_kernel<0, true><<<dim3(Dn / 64, NTOK / 64), dim3(256), 0, stream>>>(
            ao, wo + (size_t)l * Dn * Dn, bo + l * Dn, x, x, NTOK, Dn, Dn);
        ln_kernel<<<dim3(NTOK), dim3(256), 0, stream>>>(x, ln2g + l * Dn, ln2b + l * Dn, h);
        gemm_kernel<1, false><<<dim3(FFn / 64, NTOK / 64), dim3(256), 0, stream>>>(
            h, w1 + (size_t)l * Dn * FFn, b1 + l * FFn, nullptr, mid, NTOK, FFn, Dn);
        gemm_kernel<0, true><<<dim3(Dn / 64, NTOK / 64), dim3(256), 0, stream>>>(
            mid, w2 + (size_t)l * FFn * Dn, b2 + l * Dn, x, x, NTOK, Dn, FFn);
    }

    ln_kernel<<<dim3(NTOK), dim3(256), 0, stream>>>(x, lnfg, lnfb, h);
    gemm_kernel<0, false><<<dim3(Vn / 64, NTOK / 64), dim3(256), 0, stream>>>(
        h, lmw, lmb, nullptr, out, NTOK, Vn, Dn);
}